// Round 1
// baseline (1476.932 us; speedup 1.0000x reference)
//
#include <hip/hip_runtime.h>
#include <cfloat>
#include <cmath>

#define VOCAB 8192
#define MTOT 16384
#define CDIM 256
#define BMAIN 128           // rows per block in dist kernel
#define BN 128              // k columns per tile
#define CC 32               // c chunk
#define KSPLIT 8
#define KRANGE (VOCAB / KSPLIT)   // 1024
#define NTILE (KRANGE / BN)       // 8
#define TAU 2e-3f

// ---------------- enorm: ||e_k||^2 in fp64 (+fp32 copy) ----------------
__global__ void vq_enorm_kernel(const float* __restrict__ emb,
                                float* __restrict__ enorm,
                                double* __restrict__ enormd) {
  __shared__ double sd[4][64];
  int tid = threadIdx.x;
  int kk = tid & 63, cg = tid >> 6;
  int k = blockIdx.x * 64 + kk;
  double s = 0.0;
  for (int c = cg * 64; c < cg * 64 + 64; ++c) {
    float v = emb[(size_t)c * VOCAB + k];
    s += (double)v * (double)v;
  }
  sd[cg][kk] = s;
  __syncthreads();
  if (cg == 0) {
    double t = sd[0][kk] + sd[1][kk] + sd[2][kk] + sd[3][kk];
    enorm[k] = (float)t;
    enormd[k] = t;
  }
}

// ---------------- transpose emb [C][K] -> embT [K][C] ----------------
__global__ void vq_transpose_kernel(const float* __restrict__ emb,
                                    float* __restrict__ embT) {
  __shared__ float t[32][33];
  int bc = blockIdx.x & 7;    // C/32 = 8
  int bk = blockIdx.x >> 3;   // K/32 = 256
  int lx = threadIdx.x & 31, lyq = threadIdx.x >> 5;
#pragma unroll
  for (int yy = 0; yy < 4; ++yy) {
    int y = lyq * 4 + yy;
    t[y][lx] = emb[(size_t)(bc * 32 + y) * VOCAB + bk * 32 + lx];
  }
  __syncthreads();
#pragma unroll
  for (int yy = 0; yy < 4; ++yy) {
    int y = lyq * 4 + yy;
    embT[(size_t)(bk * 32 + y) * CDIM + bc * 32 + lx] = t[lx][y];
  }
}

// ---------------- fused distance GEMM + per-row best/second argmin ----------------
__global__ __launch_bounds__(256, 2) void vq_dist_kernel(
    const float* __restrict__ x, const float* __restrict__ emb,
    const float* __restrict__ enorm,
    float* __restrict__ pmin, float* __restrict__ psec, int* __restrict__ pidx) {
  __shared__ float xs[BMAIN][CC + 4];   // [128][36] floats, 16B-aligned rows
  __shared__ float es[CC][BN];          // [32][128]
  const int tid = threadIdx.x;
  const int tx = tid & 15;
  const int ty = tid >> 4;
  const int rb = blockIdx.x >> 3;       // row block 0..127
  const int sp = blockIdx.x & 7;        // k split 0..7
  const int m0 = rb * BMAIN;
  const int k0 = sp * KRANGE;

  float bv[8], sv[8];
  int bi[8];
#pragma unroll
  for (int i = 0; i < 8; ++i) { bv[i] = FLT_MAX; sv[i] = FLT_MAX; bi[i] = 0; }

  for (int kt = 0; kt < NTILE; ++kt) {
    const int kb = k0 + kt * BN;
    float acc[8][8];
#pragma unroll
    for (int i = 0; i < 8; ++i)
#pragma unroll
      for (int j = 0; j < 8; ++j) acc[i][j] = 0.f;

    for (int cc = 0; cc < CDIM; cc += CC) {
      __syncthreads();
#pragma unroll
      for (int l = 0; l < 4; ++l) {
        int f = tid + l * 256;
        int r = f >> 3, c4 = f & 7;
        float4 v = *(const float4*)(x + (size_t)(m0 + r) * CDIM + cc + c4 * 4);
        *(float4*)&xs[r][c4 * 4] = v;
      }
#pragma unroll
      for (int l = 0; l < 4; ++l) {
        int f = tid + l * 256;
        int r = f >> 5, k4 = f & 31;
        float4 v = *(const float4*)(emb + (size_t)(cc + r) * VOCAB + kb + k4 * 4);
        *(float4*)&es[r][k4 * 4] = v;
      }
      __syncthreads();
#pragma unroll
      for (int c4 = 0; c4 < CC / 4; ++c4) {
        float xa[8][4];
#pragma unroll
        for (int i = 0; i < 8; ++i)
          *(float4*)xa[i] = *(const float4*)&xs[ty * 8 + i][c4 * 4];
        float eb[4][8];
#pragma unroll
        for (int u = 0; u < 4; ++u) {
          *(float4*)&eb[u][0] = *(const float4*)&es[c4 * 4 + u][tx * 8];
          *(float4*)&eb[u][4] = *(const float4*)&es[c4 * 4 + u][tx * 8 + 4];
        }
#pragma unroll
        for (int u = 0; u < 4; ++u)
#pragma unroll
          for (int i = 0; i < 8; ++i)
#pragma unroll
            for (int j = 0; j < 8; ++j)
              acc[i][j] = fmaf(xa[i][u], eb[u][j], acc[i][j]);
      }
    }
    float en[8];
    *(float4*)&en[0] = *(const float4*)(enorm + kb + tx * 8);
    *(float4*)&en[4] = *(const float4*)(enorm + kb + tx * 8 + 4);
#pragma unroll
    for (int i = 0; i < 8; ++i)
#pragma unroll
      for (int j = 0; j < 8; ++j) {
        float d = fmaf(-2.f, acc[i][j], en[j]);
        if (d < bv[i]) { sv[i] = bv[i]; bv[i] = d; bi[i] = kb + tx * 8 + j; }
        else if (d < sv[i]) sv[i] = d;
      }
  }
  // cross-thread (tx) reduce per row, keeping best + second-best
  __syncthreads();
  float* red_b = &xs[0][0];          // 2048 floats
  float* red_s = red_b + 2048;       // 2048 floats (fits in 4608)
  int* red_i = (int*)&es[0][0];      // 2048 ints
#pragma unroll
  for (int i = 0; i < 8; ++i) {
    int row = ty * 8 + i;
    red_b[row * 16 + tx] = bv[i];
    red_s[row * 16 + tx] = sv[i];
    red_i[row * 16 + tx] = bi[i];
  }
  __syncthreads();
  if (tid < BMAIN) {
    int row = tid;
    float B = red_b[row * 16], S = red_s[row * 16];
    int I = red_i[row * 16];
    for (int t = 1; t < 16; ++t) {
      float b = red_b[row * 16 + t];
      float s2 = red_s[row * 16 + t];
      int i2 = red_i[row * 16 + t];
      if (b < B) { S = fminf(B, s2); B = b; I = i2; }
      else {
        S = fminf(S, fminf(b, s2));
        if (b == B && i2 < I) I = i2;
      }
    }
    pmin[sp * MTOT + m0 + row] = B;
    psec[sp * MTOT + m0 + row] = S;
    pidx[sp * MTOT + m0 + row] = I;
  }
}

// ---------------- final argmin merge + fp64 rescan for near-ties + gather ----------------
__global__ void vq_gather_kernel(
    const float* __restrict__ x, const float* __restrict__ emb,
    const float* __restrict__ embT,   // may be null
    const double* __restrict__ enormd,
    const float* __restrict__ pmin, const float* __restrict__ psec,
    const int* __restrict__ pidx,
    float* __restrict__ out, int* __restrict__ counts, float* __restrict__ ssep) {
  __shared__ float xrow[CDIM];
  __shared__ double rbd[256];
  __shared__ int rbi[256];
  __shared__ float warp_s[4];
  __shared__ int best_sh;
  const int m = blockIdx.x;
  const int tid = threadIdx.x;

  float B = FLT_MAX, S = FLT_MAX;
  int I = 0;
#pragma unroll
  for (int sp2 = 0; sp2 < KSPLIT; ++sp2) {
    float b = pmin[sp2 * MTOT + m];
    float s2 = psec[sp2 * MTOT + m];
    int i2 = pidx[sp2 * MTOT + m];
    if (b < B) { S = fminf(B, s2); B = b; I = i2; }
    else { S = fminf(S, fminf(b, s2)); if (b == B && i2 < I) I = i2; }
  }
  int best = I;
  xrow[tid] = x[(size_t)m * CDIM + tid];
  __syncthreads();
  if (S - B < TAU) {   // block-uniform condition: exact fp64 rescan of all codes
    double bd = DBL_MAX;
    int bidx = VOCAB;
    for (int t = 0; t < VOCAB / 256; ++t) {
      int k = tid + t * 256;
      double dot = 0.0;
      for (int c = 0; c < CDIM; ++c)
        dot += (double)xrow[c] * (double)emb[(size_t)c * VOCAB + k];
      double d = enormd[k] - 2.0 * dot;
      if (d < bd) { bd = d; bidx = k; }   // per-thread k ascending -> first occurrence
    }
    rbd[tid] = bd; rbi[tid] = bidx;
    __syncthreads();
    if (tid == 0) {
      double bb = rbd[0]; int ii = rbi[0];
      for (int t = 1; t < 256; ++t)
        if (rbd[t] < bb || (rbd[t] == bb && rbi[t] < ii)) { bb = rbd[t]; ii = rbi[t]; }
      best_sh = ii;
    }
    __syncthreads();
    best = best_sh;
  }
  float q = embT ? embT[(size_t)best * CDIM + tid]
                 : emb[(size_t)tid * VOCAB + best];
  float xv = xrow[tid];
  float df = q - xv;
  out[(size_t)m * CDIM + tid] = q;
  float v = df * df;
#pragma unroll
  for (int off = 32; off > 0; off >>= 1) v += __shfl_down(v, off, 64);
  int lane = tid & 63, wid = tid >> 6;
  if (lane == 0) warp_s[wid] = v;
  __syncthreads();
  if (tid == 0) {
    ssep[m] = warp_s[0] + warp_s[1] + warp_s[2] + warp_s[3];
    atomicAdd(&counts[best], 1);
  }
}

// ---------------- loss + perplexity ----------------
__global__ void vq_finalize_kernel(const float* __restrict__ ssep,
                                   const int* __restrict__ counts,
                                   float* __restrict__ out) {
  __shared__ double red[256];
  const int tid = threadIdx.x;
  double s = 0.0;
  for (int i = tid; i < MTOT; i += 256) s += (double)ssep[i];
  red[tid] = s;
  __syncthreads();
  for (int off = 128; off > 0; off >>= 1) {
    if (tid < off) red[tid] += red[tid + off];
    __syncthreads();
  }
  double sse = red[0];
  __syncthreads();
  double ps = 0.0;
  for (int k = tid; k < VOCAB; k += 256) {
    double p = (double)counts[k] / (double)MTOT;
    ps += p * log(p + 1e-10);
  }
  red[tid] = ps;
  __syncthreads();
  for (int off = 128; off > 0; off >>= 1) {
    if (tid < off) red[tid] += red[tid + off];
    __syncthreads();
  }
  if (tid == 0) {
    out[(size_t)MTOT * CDIM] = (float)(1.25 * sse / (double)((size_t)MTOT * CDIM));
    out[(size_t)MTOT * CDIM + 1] = (float)exp(-red[0]);
  }
}

extern "C" void kernel_launch(void* const* d_in, const int* in_sizes, int n_in,
                              void* d_out, int out_size, void* d_ws, size_t ws_size,
                              hipStream_t stream) {
  const float* x = (const float*)d_in[0];
  const float* emb = (const float*)d_in[1];
  float* out = (float*)d_out;
  char* ws = (char*)d_ws;

  // workspace layout (bytes)
  double* enormd = (double*)(ws);                 //      0: 8192*8   = 65536
  float* enorm   = (float*)(ws + 65536);          //  65536: 8192*4   = 32768
  float* pmin    = (float*)(ws + 98304);          //  98304: 8*16384*4= 524288
  float* psec    = (float*)(ws + 622592);         // 622592: 524288
  int* pidx      = (int*)(ws + 1146880);          // 1146880: 524288
  int* counts    = (int*)(ws + 1671168);          // 1671168: 32768
  float* ssep    = (float*)(ws + 1703936);        // 1703936: 65536
  const size_t base_need = 1769472;
  const size_t embT_need = base_need + (size_t)VOCAB * CDIM * 4;  // + 8 MiB
  float* embT = (ws_size >= embT_need) ? (float*)(ws + base_need) : nullptr;

  hipMemsetAsync(counts, 0, VOCAB * sizeof(int), stream);
  vq_enorm_kernel<<<VOCAB / 64, 256, 0, stream>>>(emb, enorm, enormd);
  if (embT)
    vq_transpose_kernel<<<(VOCAB / 32) * (CDIM / 32), 256, 0, stream>>>(emb, embT);
  vq_dist_kernel<<<(MTOT / BMAIN) * KSPLIT, 256, 0, stream>>>(x, emb, enorm,
                                                              pmin, psec, pidx);
  vq_gather_kernel<<<MTOT, 256, 0, stream>>>(x, emb, embT, enormd,
                                             pmin, psec, pidx, out, counts, ssep);
  vq_finalize_kernel<<<1, 256, 0, stream>>>(ssep, counts, out);
}

// Round 2
// 875.145 us; speedup vs baseline: 1.6876x; 1.6876x over previous
//
#include <hip/hip_runtime.h>
#include <cfloat>
#include <cmath>

#define VOCAB 8192
#define MTOT 16384
#define CDIM 256
#define BMAIN 128
#define BN 128
#define CC 32
#define KSPLIT 8
#define KRANGE (VOCAB / KSPLIT)   // 1024
#define NTILE (KRANGE / BN)       // 8
#define TAU 2e-3f

typedef __attribute__((ext_vector_type(8))) short bf16x8;
typedef __attribute__((ext_vector_type(4))) float f32x4;

__device__ inline ushort f2bf(float f) {
  unsigned u = __float_as_uint(f);
  unsigned r = (u + 0x7fffu + ((u >> 16) & 1u)) >> 16;
  return (ushort)r;
}
__device__ inline float bf2f(ushort h) { return __uint_as_float(((unsigned)h) << 16); }

// ---------------- enorm: ||e_k||^2 in fp64 (+fp32 copy) ----------------
__global__ void vq_enorm_kernel(const float* __restrict__ emb,
                                float* __restrict__ enorm,
                                double* __restrict__ enormd) {
  __shared__ double sd[4][64];
  int tid = threadIdx.x;
  int kk = tid & 63, cg = tid >> 6;
  int k = blockIdx.x * 64 + kk;
  double s = 0.0;
  for (int c = cg * 64; c < cg * 64 + 64; ++c) {
    float v = emb[(size_t)c * VOCAB + k];
    s += (double)v * (double)v;
  }
  sd[cg][kk] = s;
  __syncthreads();
  if (cg == 0) {
    double t = sd[0][kk] + sd[1][kk] + sd[2][kk] + sd[3][kk];
    enorm[k] = (float)t;
    enormd[k] = t;
  }
}

// ---------------- x -> bf16 hi/lo planes ----------------
__global__ void vq_prep_x_kernel(const float* __restrict__ x,
                                 ushort* __restrict__ xhi, ushort* __restrict__ xlo) {
  int t = blockIdx.x * 256 + threadIdx.x;  // 8 elems per thread
  const float4* xp = (const float4*)x + (size_t)t * 2;
  float4 v0 = xp[0], v1 = xp[1];
  float a[8] = {v0.x, v0.y, v0.z, v0.w, v1.x, v1.y, v1.z, v1.w};
  bf16x8 h, l;
#pragma unroll
  for (int j = 0; j < 8; ++j) {
    ushort hu = f2bf(a[j]);
    h[j] = (short)hu;
    l[j] = (short)f2bf(a[j] - bf2f(hu));
  }
  *(bf16x8*)(xhi + (size_t)t * 8) = h;
  *(bf16x8*)(xlo + (size_t)t * 8) = l;
}

// ---------------- emb -> embT fp32 + bf16 hi/lo planes [K][C] ----------------
__global__ void vq_prep_embT_kernel(const float* __restrict__ emb,
                                    float* __restrict__ embT,
                                    ushort* __restrict__ ehi, ushort* __restrict__ elo) {
  __shared__ float t[32][33];
  int bc = blockIdx.x & 7;    // C/32 = 8
  int bk = blockIdx.x >> 3;   // K/32 = 256
  int lx = threadIdx.x & 31, lyq = threadIdx.x >> 5;
#pragma unroll
  for (int yy = 0; yy < 4; ++yy) {
    int y = lyq * 4 + yy;
    t[y][lx] = emb[(size_t)(bc * 32 + y) * VOCAB + bk * 32 + lx];
  }
  __syncthreads();
#pragma unroll
  for (int yy = 0; yy < 4; ++yy) {
    int y = lyq * 4 + yy;
    float v = t[lx][y];
    size_t o = (size_t)(bk * 32 + y) * CDIM + bc * 32 + lx;
    embT[o] = v;
    ushort hu = f2bf(v);
    ehi[o] = hu;
    elo[o] = f2bf(v - bf2f(hu));
  }
}

// ---------------- MFMA distance + per-row best/second argmin ----------------
// S = X * E^T via split-bf16 (3 MFMA terms); d = enorm - 2S.
__global__ __launch_bounds__(256, 2) void vq_dist_mfma_kernel(
    const ushort* __restrict__ xhi, const ushort* __restrict__ xlo,
    const ushort* __restrict__ ehi, const ushort* __restrict__ elo,
    const float* __restrict__ enorm,
    float* __restrict__ pmin, float* __restrict__ psec, int* __restrict__ pidx) {
  __shared__ ushort Ah[128][40], Al[128][40], Bh[128][40], Bl[128][40];  // pad 32->40: conflict-free
  __shared__ float lb[2][128], ls[2][128];
  __shared__ int li[2][128];
  const int tid = threadIdx.x;
  const int lane = tid & 63, wid = tid >> 6;
  const int wr = wid >> 1, wc = wid & 1;
  const int rb = blockIdx.x >> 3, sp = blockIdx.x & 7;
  const int m0 = rb * 128;
  const int l15 = lane & 15, lg = lane >> 4;
  const int ko = lg * 8;

  float bv[4][4], sv[4][4];
  int bi[4][4];
#pragma unroll
  for (int mf = 0; mf < 4; ++mf)
#pragma unroll
    for (int r = 0; r < 4; ++r) { bv[mf][r] = FLT_MAX; sv[mf][r] = FLT_MAX; bi[mf][r] = 0; }

  for (int kt = 0; kt < NTILE; ++kt) {
    const int n0 = sp * KRANGE + kt * 128;
    f32x4 acc[4][4];
#pragma unroll
    for (int mf = 0; mf < 4; ++mf)
#pragma unroll
      for (int nf = 0; nf < 4; ++nf) acc[mf][nf] = (f32x4)0.f;

    for (int cs = 0; cs < 8; ++cs) {
      __syncthreads();
#pragma unroll
      for (int l = 0; l < 2; ++l) {
        int flat = tid + l * 256;
        int r = flat >> 2, c8 = (flat & 3) * 8;
        size_t ga = (size_t)(m0 + r) * CDIM + cs * 32 + c8;
        *(bf16x8*)&Ah[r][c8] = *(const bf16x8*)(xhi + ga);
        *(bf16x8*)&Al[r][c8] = *(const bf16x8*)(xlo + ga);
        size_t gb = (size_t)(n0 + r) * CDIM + cs * 32 + c8;
        *(bf16x8*)&Bh[r][c8] = *(const bf16x8*)(ehi + gb);
        *(bf16x8*)&Bl[r][c8] = *(const bf16x8*)(elo + gb);
      }
      __syncthreads();
      bf16x8 bhf[4], blf[4];
#pragma unroll
      for (int nf = 0; nf < 4; ++nf) {
        int bcol = wc * 64 + nf * 16 + l15;
        bhf[nf] = *(const bf16x8*)&Bh[bcol][ko];
        blf[nf] = *(const bf16x8*)&Bl[bcol][ko];
      }
#pragma unroll
      for (int mf = 0; mf < 4; ++mf) {
        int arow = wr * 64 + mf * 16 + l15;
        bf16x8 ahf = *(const bf16x8*)&Ah[arow][ko];
        bf16x8 alf = *(const bf16x8*)&Al[arow][ko];
#pragma unroll
        for (int nf = 0; nf < 4; ++nf) {
          acc[mf][nf] = __builtin_amdgcn_mfma_f32_16x16x32_bf16(ahf, bhf[nf], acc[mf][nf], 0, 0, 0);
          acc[mf][nf] = __builtin_amdgcn_mfma_f32_16x16x32_bf16(ahf, blf[nf], acc[mf][nf], 0, 0, 0);
          acc[mf][nf] = __builtin_amdgcn_mfma_f32_16x16x32_bf16(alf, bhf[nf], acc[mf][nf], 0, 0, 0);
        }
      }
    }
    // d = enorm - 2S, update per-lane best/second
#pragma unroll
    for (int nf = 0; nf < 4; ++nf) {
      int n = n0 + wc * 64 + nf * 16 + l15;
      float en = enorm[n];
#pragma unroll
      for (int mf = 0; mf < 4; ++mf)
#pragma unroll
        for (int r = 0; r < 4; ++r) {
          float d = fmaf(-2.f, acc[mf][nf][r], en);
          if (d < bv[mf][r]) { sv[mf][r] = bv[mf][r]; bv[mf][r] = d; bi[mf][r] = n; }
          else sv[mf][r] = fminf(sv[mf][r], d);
        }
    }
  }
  // reduce across 16-lane groups (same rows, different cols)
#pragma unroll
  for (int mf = 0; mf < 4; ++mf)
#pragma unroll
    for (int r = 0; r < 4; ++r) {
      float b = bv[mf][r], s = sv[mf][r];
      int i = bi[mf][r];
#pragma unroll
      for (int m = 1; m < 16; m <<= 1) {
        float ob = __shfl_xor(b, m, 64);
        float os = __shfl_xor(s, m, 64);
        int oi = __shfl_xor(i, m, 64);
        if (ob < b) { s = fminf(b, os); b = ob; i = oi; }
        else if (ob == b) { i = min(i, oi); s = fminf(fminf(s, os), b); }  // dup value -> gap 0 -> rescan
        else s = fminf(s, fminf(ob, os));
      }
      bv[mf][r] = b; sv[mf][r] = s; bi[mf][r] = i;
    }
  if (l15 == 0) {
#pragma unroll
    for (int mf = 0; mf < 4; ++mf)
#pragma unroll
      for (int r = 0; r < 4; ++r) {
        int row = wr * 64 + mf * 16 + lg * 4 + r;
        lb[wc][row] = bv[mf][r]; ls[wc][row] = sv[mf][r]; li[wc][row] = bi[mf][r];
      }
  }
  __syncthreads();
  if (tid < 128) {
    float b = lb[0][tid], s = ls[0][tid];
    int i = li[0][tid];
    float ob = lb[1][tid], os = ls[1][tid];
    int oi = li[1][tid];
    if (ob < b) { s = fminf(b, os); b = ob; i = oi; }
    else if (ob == b) { i = min(i, oi); s = fminf(fminf(s, os), b); }
    else s = fminf(s, fminf(ob, os));
    pmin[sp * MTOT + m0 + tid] = b;
    psec[sp * MTOT + m0 + tid] = s;
    pidx[sp * MTOT + m0 + tid] = i;
  }
}

// ---------------- fp32 fallback dist kernel (round-1 code) ----------------
__global__ __launch_bounds__(256, 2) void vq_dist_kernel(
    const float* __restrict__ x, const float* __restrict__ emb,
    const float* __restrict__ enorm,
    float* __restrict__ pmin, float* __restrict__ psec, int* __restrict__ pidx) {
  __shared__ float xs[BMAIN][CC + 4];
  __shared__ float es[CC][BN];
  const int tid = threadIdx.x;
  const int tx = tid & 15;
  const int ty = tid >> 4;
  const int rb = blockIdx.x >> 3;
  const int sp = blockIdx.x & 7;
  const int m0 = rb * BMAIN;
  const int k0 = sp * KRANGE;

  float bv[8], sv[8];
  int bi[8];
#pragma unroll
  for (int i = 0; i < 8; ++i) { bv[i] = FLT_MAX; sv[i] = FLT_MAX; bi[i] = 0; }

  for (int kt = 0; kt < NTILE; ++kt) {
    const int kb = k0 + kt * BN;
    float acc[8][8];
#pragma unroll
    for (int i = 0; i < 8; ++i)
#pragma unroll
      for (int j = 0; j < 8; ++j) acc[i][j] = 0.f;

    for (int cc = 0; cc < CDIM; cc += CC) {
      __syncthreads();
#pragma unroll
      for (int l = 0; l < 4; ++l) {
        int f = tid + l * 256;
        int r = f >> 3, c4 = f & 7;
        float4 v = *(const float4*)(x + (size_t)(m0 + r) * CDIM + cc + c4 * 4);
        *(float4*)&xs[r][c4 * 4] = v;
      }
#pragma unroll
      for (int l = 0; l < 4; ++l) {
        int f = tid + l * 256;
        int r = f >> 5, k4 = f & 31;
        float4 v = *(const float4*)(emb + (size_t)(cc + r) * VOCAB + kb + k4 * 4);
        *(float4*)&es[r][k4 * 4] = v;
      }
      __syncthreads();
#pragma unroll
      for (int c4 = 0; c4 < CC / 4; ++c4) {
        float xa[8][4];
#pragma unroll
        for (int i = 0; i < 8; ++i)
          *(float4*)xa[i] = *(const float4*)&xs[ty * 8 + i][c4 * 4];
        float eb[4][8];
#pragma unroll
        for (int u = 0; u < 4; ++u) {
          *(float4*)&eb[u][0] = *(const float4*)&es[c4 * 4 + u][tx * 8];
          *(float4*)&eb[u][4] = *(const float4*)&es[c4 * 4 + u][tx * 8 + 4];
        }
#pragma unroll
        for (int u = 0; u < 4; ++u)
#pragma unroll
          for (int i = 0; i < 8; ++i)
#pragma unroll
            for (int j = 0; j < 8; ++j)
              acc[i][j] = fmaf(xa[i][u], eb[u][j], acc[i][j]);
      }
    }
    float en[8];
    *(float4*)&en[0] = *(const float4*)(enorm + kb + tx * 8);
    *(float4*)&en[4] = *(const float4*)(enorm + kb + tx * 8 + 4);
#pragma unroll
    for (int i = 0; i < 8; ++i)
#pragma unroll
      for (int j = 0; j < 8; ++j) {
        float d = fmaf(-2.f, acc[i][j], en[j]);
        if (d < bv[i]) { sv[i] = bv[i]; bv[i] = d; bi[i] = kb + tx * 8 + j; }
        else if (d < sv[i]) sv[i] = d;
      }
  }
  __syncthreads();
  float* red_b = &xs[0][0];
  float* red_s = red_b + 2048;
  int* red_i = (int*)&es[0][0];
#pragma unroll
  for (int i = 0; i < 8; ++i) {
    int row = ty * 8 + i;
    red_b[row * 16 + tx] = bv[i];
    red_s[row * 16 + tx] = sv[i];
    red_i[row * 16 + tx] = bi[i];
  }
  __syncthreads();
  if (tid < BMAIN) {
    int row = tid;
    float B = red_b[row * 16], S = red_s[row * 16];
    int I = red_i[row * 16];
    for (int t = 1; t < 16; ++t) {
      float b = red_b[row * 16 + t];
      float s2 = red_s[row * 16 + t];
      int i2 = red_i[row * 16 + t];
      if (b < B) { S = fminf(B, s2); B = b; I = i2; }
      else {
        S = fminf(S, fminf(b, s2));
        if (b == B && i2 < I) I = i2;
      }
    }
    pmin[sp * MTOT + m0 + row] = B;
    psec[sp * MTOT + m0 + row] = S;
    pidx[sp * MTOT + m0 + row] = I;
  }
}

// ---------------- fallback transpose ----------------
__global__ void vq_transpose_kernel(const float* __restrict__ emb,
                                    float* __restrict__ embT) {
  __shared__ float t[32][33];
  int bc = blockIdx.x & 7;
  int bk = blockIdx.x >> 3;
  int lx = threadIdx.x & 31, lyq = threadIdx.x >> 5;
#pragma unroll
  for (int yy = 0; yy < 4; ++yy) {
    int y = lyq * 4 + yy;
    t[y][lx] = emb[(size_t)(bc * 32 + y) * VOCAB + bk * 32 + lx];
  }
  __syncthreads();
#pragma unroll
  for (int yy = 0; yy < 4; ++yy) {
    int y = lyq * 4 + yy;
    embT[(size_t)(bk * 32 + y) * CDIM + bc * 32 + lx] = t[lx][y];
  }
}

// ---------------- final argmin merge + fp64 rescan for near-ties + gather ----------------
__global__ void vq_gather_kernel(
    const float* __restrict__ x, const float* __restrict__ emb,
    const float* __restrict__ embT,
    const double* __restrict__ enormd,
    const float* __restrict__ pmin, const float* __restrict__ psec,
    const int* __restrict__ pidx,
    float* __restrict__ out, int* __restrict__ counts, float* __restrict__ ssep) {
  __shared__ float xrow[CDIM];
  __shared__ double rbd[256];
  __shared__ int rbi[256];
  __shared__ float warp_s[4];
  __shared__ int best_sh;
  const int m = blockIdx.x;
  const int tid = threadIdx.x;

  float B = FLT_MAX, S = FLT_MAX;
  int I = 0;
#pragma unroll
  for (int sp2 = 0; sp2 < KSPLIT; ++sp2) {
    float b = pmin[sp2 * MTOT + m];
    float s2 = psec[sp2 * MTOT + m];
    int i2 = pidx[sp2 * MTOT + m];
    if (b < B) { S = fminf(B, s2); B = b; I = i2; }
    else { S = fminf(S, fminf(b, s2)); if (b == B && i2 < I) I = i2; }
  }
  int best = I;
  xrow[tid] = x[(size_t)m * CDIM + tid];
  __syncthreads();
  if (S - B < TAU) {
    double bd = DBL_MAX;
    int bidx = VOCAB;
    for (int t = 0; t < VOCAB / 256; ++t) {
      int k = tid + t * 256;
      double dot = 0.0;
      for (int c = 0; c < CDIM; ++c)
        dot += (double)xrow[c] * (double)emb[(size_t)c * VOCAB + k];
      double d = enormd[k] - 2.0 * dot;
      if (d < bd) { bd = d; bidx = k; }
    }
    rbd[tid] = bd; rbi[tid] = bidx;
    __syncthreads();
    if (tid == 0) {
      double bb = rbd[0]; int ii = rbi[0];
      for (int t = 1; t < 256; ++t)
        if (rbd[t] < bb || (rbd[t] == bb && rbi[t] < ii)) { bb = rbd[t]; ii = rbi[t]; }
      best_sh = ii;
    }
    __syncthreads();
    best = best_sh;
  }
  float q = embT ? embT[(size_t)best * CDIM + tid]
                 : emb[(size_t)tid * VOCAB + best];
  float xv = xrow[tid];
  float df = q - xv;
  out[(size_t)m * CDIM + tid] = q;
  float v = df * df;
#pragma unroll
  for (int off = 32; off > 0; off >>= 1) v += __shfl_down(v, off, 64);
  int lane = tid & 63, wid = tid >> 6;
  if (lane == 0) warp_s[wid] = v;
  __syncthreads();
  if (tid == 0) {
    ssep[m] = warp_s[0] + warp_s[1] + warp_s[2] + warp_s[3];
    atomicAdd(&counts[best], 1);
  }
}

// ---------------- loss + perplexity ----------------
__global__ void vq_finalize_kernel(const float* __restrict__ ssep,
                                   const int* __restrict__ counts,
                                   float* __restrict__ out) {
  __shared__ double red[256];
  const int tid = threadIdx.x;
  double s = 0.0;
  for (int i = tid; i < MTOT; i += 256) s += (double)ssep[i];
  red[tid] = s;
  __syncthreads();
  for (int off = 128; off > 0; off >>= 1) {
    if (tid < off) red[tid] += red[tid + off];
    __syncthreads();
  }
  double sse = red[0];
  __syncthreads();
  double ps = 0.0;
  for (int k = tid; k < VOCAB; k += 256) {
    double p = (double)counts[k] / (double)MTOT;
    ps += p * log(p + 1e-10);
  }
  red[tid] = ps;
  __syncthreads();
  for (int off = 128; off > 0; off >>= 1) {
    if (tid < off) red[tid] += red[tid + off];
    __syncthreads();
  }
  if (tid == 0) {
    out[(size_t)MTOT * CDIM] = (float)(1.25 * sse / (double)((size_t)MTOT * CDIM));
    out[(size_t)MTOT * CDIM + 1] = (float)exp(-red[0]);
  }
}

extern "C" void kernel_launch(void* const* d_in, const int* in_sizes, int n_in,
                              void* d_out, int out_size, void* d_ws, size_t ws_size,
                              hipStream_t stream) {
  const float* x = (const float*)d_in[0];
  const float* emb = (const float*)d_in[1];
  float* out = (float*)d_out;
  char* ws = (char*)d_ws;

  // workspace layout (bytes)
  double* enormd = (double*)(ws);                 //        0: 65536
  float* enorm   = (float*)(ws + 65536);          //    65536: 32768
  float* pmin    = (float*)(ws + 98304);          //    98304: 524288
  float* psec    = (float*)(ws + 622592);         //   622592: 524288
  int* pidx      = (int*)(ws + 1146880);          //  1146880: 524288
  int* counts    = (int*)(ws + 1671168);          //  1671168: 32768
  float* ssep    = (float*)(ws + 1703936);        //  1703936: 65536
  const size_t base_need = 1769472;
  float* embT   = (float*)(ws + base_need);       //  1769472: 8388608
  ushort* xhi   = (ushort*)(ws + 10158080);       // 10158080: 8388608
  ushort* xlo   = (ushort*)(ws + 18546688);       // 18546688: 8388608
  ushort* ehi   = (ushort*)(ws + 26935296);       // 26935296: 4194304
  ushort* elo   = (ushort*)(ws + 31129600);       // 31129600: 4194304
  const size_t full_need = 35323904;
  const size_t embT_need = base_need + 8388608;

  hipMemsetAsync(counts, 0, VOCAB * sizeof(int), stream);
  vq_enorm_kernel<<<VOCAB / 64, 256, 0, stream>>>(emb, enorm, enormd);

  if (ws_size >= full_need) {
    // fast path: split-bf16 MFMA distance GEMM
    vq_prep_x_kernel<<<(MTOT * CDIM) / 2048, 256, 0, stream>>>(x, xhi, xlo);
    vq_prep_embT_kernel<<<(VOCAB / 32) * (CDIM / 32), 256, 0, stream>>>(emb, embT, ehi, elo);
    vq_dist_mfma_kernel<<<(MTOT / 128) * KSPLIT, 256, 0, stream>>>(xhi, xlo, ehi, elo, enorm,
                                                                   pmin, psec, pidx);
    vq_gather_kernel<<<MTOT, 256, 0, stream>>>(x, emb, embT, enormd,
                                               pmin, psec, pidx, out, counts, ssep);
  } else {
    float* embT_fb = (ws_size >= embT_need) ? embT : nullptr;
    if (embT_fb)
      vq_transpose_kernel<<<(VOCAB / 32) * (CDIM / 32), 256, 0, stream>>>(emb, embT_fb);
    vq_dist_kernel<<<(MTOT / BMAIN) * KSPLIT, 256, 0, stream>>>(x, emb, enorm,
                                                                pmin, psec, pidx);
    vq_gather_kernel<<<MTOT, 256, 0, stream>>>(x, emb, embT_fb, enormd,
                                               pmin, psec, pidx, out, counts, ssep);
  }
  vq_finalize_kernel<<<1, 256, 0, stream>>>(ssep, counts, out);
}

// Round 3
// 473.223 us; speedup vs baseline: 3.1210x; 1.8493x over previous
//
#include <hip/hip_runtime.h>
#include <cfloat>
#include <cmath>

#define VOCAB 8192
#define MTOT 16384
#define CDIM 256
#define BMAIN 128
#define BN 128
#define CC 32
#define KSPLIT 8
#define KRANGE (VOCAB / KSPLIT)   // 1024
#define NTILE (KRANGE / BN)       // 8
#define TAU 2e-3f
#define IDX_INF 0x7fffffff

typedef __attribute__((ext_vector_type(8))) short bf16x8;
typedef __attribute__((ext_vector_type(4))) float f32x4;

__device__ inline ushort f2bf(float f) {
  unsigned u = __float_as_uint(f);
  unsigned r = (u + 0x7fffu + ((u >> 16) & 1u)) >> 16;
  return (ushort)r;
}
__device__ inline float bf2f(ushort h) { return __uint_as_float(((unsigned)h) << 16); }

// merge other top-2 (ob,oi,os,osi) into mine (b,i,s,si); order by (value, index)
__device__ inline void top2_merge(float& b, int& i, float& s, int& si,
                                  float ob, int oi, float os, int osi) {
  if (ob < b || (ob == b && oi < i)) {
    if (b < os || (b == os && i < osi)) { s = b; si = i; }
    else { s = os; si = osi; }
    b = ob; i = oi;
  } else {
    if (ob < s || (ob == s && oi < si)) { s = ob; si = oi; }
  }
}

// ---------------- enorm: ||e_k||^2 in fp64 (+fp32 copy) ----------------
__global__ void vq_enorm_kernel(const float* __restrict__ emb,
                                float* __restrict__ enorm,
                                double* __restrict__ enormd) {
  __shared__ double sd[4][64];
  int tid = threadIdx.x;
  int kk = tid & 63, cg = tid >> 6;
  int k = blockIdx.x * 64 + kk;
  double s = 0.0;
  for (int c = cg * 64; c < cg * 64 + 64; ++c) {
    float v = emb[(size_t)c * VOCAB + k];
    s += (double)v * (double)v;
  }
  sd[cg][kk] = s;
  __syncthreads();
  if (cg == 0) {
    double t = sd[0][kk] + sd[1][kk] + sd[2][kk] + sd[3][kk];
    enorm[k] = (float)t;
    enormd[k] = t;
  }
}

// ---------------- x -> bf16 hi/lo planes ----------------
__global__ void vq_prep_x_kernel(const float* __restrict__ x,
                                 ushort* __restrict__ xhi, ushort* __restrict__ xlo) {
  int t = blockIdx.x * 256 + threadIdx.x;  // 8 elems per thread
  const float4* xp = (const float4*)x + (size_t)t * 2;
  float4 v0 = xp[0], v1 = xp[1];
  float a[8] = {v0.x, v0.y, v0.z, v0.w, v1.x, v1.y, v1.z, v1.w};
  bf16x8 h, l;
#pragma unroll
  for (int j = 0; j < 8; ++j) {
    ushort hu = f2bf(a[j]);
    h[j] = (short)hu;
    l[j] = (short)f2bf(a[j] - bf2f(hu));
  }
  *(bf16x8*)(xhi + (size_t)t * 8) = h;
  *(bf16x8*)(xlo + (size_t)t * 8) = l;
}

// ---------------- emb -> embT fp32 + bf16 hi/lo planes [K][C] ----------------
__global__ void vq_prep_embT_kernel(const float* __restrict__ emb,
                                    float* __restrict__ embT,
                                    ushort* __restrict__ ehi, ushort* __restrict__ elo) {
  __shared__ float t[32][33];
  int bc = blockIdx.x & 7;    // C/32 = 8
  int bk = blockIdx.x >> 3;   // K/32 = 256
  int lx = threadIdx.x & 31, lyq = threadIdx.x >> 5;
#pragma unroll
  for (int yy = 0; yy < 4; ++yy) {
    int y = lyq * 4 + yy;
    t[y][lx] = emb[(size_t)(bc * 32 + y) * VOCAB + bk * 32 + lx];
  }
  __syncthreads();
#pragma unroll
  for (int yy = 0; yy < 4; ++yy) {
    int y = lyq * 4 + yy;
    float v = t[lx][y];
    size_t o = (size_t)(bk * 32 + y) * CDIM + bc * 32 + lx;
    embT[o] = v;
    ushort hu = f2bf(v);
    ehi[o] = hu;
    elo[o] = f2bf(v - bf2f(hu));
  }
}

// ---------------- MFMA distance + per-row top-2 (value,index) ----------------
__global__ __launch_bounds__(256, 2) void vq_dist_mfma_kernel(
    const ushort* __restrict__ xhi, const ushort* __restrict__ xlo,
    const ushort* __restrict__ ehi, const ushort* __restrict__ elo,
    const float* __restrict__ enorm,
    float* __restrict__ pmin, float* __restrict__ psec,
    int* __restrict__ pidx, int* __restrict__ psidx) {
  __shared__ ushort Ah[128][40], Al[128][40], Bh[128][40], Bl[128][40];
  __shared__ float lb[2][128], ls[2][128];
  __shared__ int li[2][128], lsi[2][128];
  const int tid = threadIdx.x;
  const int lane = tid & 63, wid = tid >> 6;
  const int wr = wid >> 1, wc = wid & 1;
  const int rb = blockIdx.x >> 3, sp = blockIdx.x & 7;
  const int m0 = rb * 128;
  const int l15 = lane & 15, lg = lane >> 4;
  const int ko = lg * 8;

  float bv[4][4], sv[4][4];
  int bi[4][4], si[4][4];
#pragma unroll
  for (int mf = 0; mf < 4; ++mf)
#pragma unroll
    for (int r = 0; r < 4; ++r) {
      bv[mf][r] = FLT_MAX; sv[mf][r] = FLT_MAX;
      bi[mf][r] = IDX_INF; si[mf][r] = IDX_INF;
    }

  for (int kt = 0; kt < NTILE; ++kt) {
    const int n0 = sp * KRANGE + kt * 128;
    f32x4 acc[4][4];
#pragma unroll
    for (int mf = 0; mf < 4; ++mf)
#pragma unroll
      for (int nf = 0; nf < 4; ++nf) acc[mf][nf] = (f32x4)0.f;

    for (int cs = 0; cs < 8; ++cs) {
      __syncthreads();
#pragma unroll
      for (int l = 0; l < 2; ++l) {
        int flat = tid + l * 256;
        int r = flat >> 2, c8 = (flat & 3) * 8;
        size_t ga = (size_t)(m0 + r) * CDIM + cs * 32 + c8;
        *(bf16x8*)&Ah[r][c8] = *(const bf16x8*)(xhi + ga);
        *(bf16x8*)&Al[r][c8] = *(const bf16x8*)(xlo + ga);
        size_t gb = (size_t)(n0 + r) * CDIM + cs * 32 + c8;
        *(bf16x8*)&Bh[r][c8] = *(const bf16x8*)(ehi + gb);
        *(bf16x8*)&Bl[r][c8] = *(const bf16x8*)(elo + gb);
      }
      __syncthreads();
      bf16x8 bhf[4], blf[4];
#pragma unroll
      for (int nf = 0; nf < 4; ++nf) {
        int bcol = wc * 64 + nf * 16 + l15;
        bhf[nf] = *(const bf16x8*)&Bh[bcol][ko];
        blf[nf] = *(const bf16x8*)&Bl[bcol][ko];
      }
#pragma unroll
      for (int mf = 0; mf < 4; ++mf) {
        int arow = wr * 64 + mf * 16 + l15;
        bf16x8 ahf = *(const bf16x8*)&Ah[arow][ko];
        bf16x8 alf = *(const bf16x8*)&Al[arow][ko];
#pragma unroll
        for (int nf = 0; nf < 4; ++nf) {
          acc[mf][nf] = __builtin_amdgcn_mfma_f32_16x16x32_bf16(ahf, bhf[nf], acc[mf][nf], 0, 0, 0);
          acc[mf][nf] = __builtin_amdgcn_mfma_f32_16x16x32_bf16(ahf, blf[nf], acc[mf][nf], 0, 0, 0);
          acc[mf][nf] = __builtin_amdgcn_mfma_f32_16x16x32_bf16(alf, bhf[nf], acc[mf][nf], 0, 0, 0);
        }
      }
    }
#pragma unroll
    for (int nf = 0; nf < 4; ++nf) {
      int n = n0 + wc * 64 + nf * 16 + l15;
      float en = enorm[n];
#pragma unroll
      for (int mf = 0; mf < 4; ++mf)
#pragma unroll
        for (int r = 0; r < 4; ++r) {
          float d = fmaf(-2.f, acc[mf][nf][r], en);
          if (d < bv[mf][r]) {
            sv[mf][r] = bv[mf][r]; si[mf][r] = bi[mf][r];
            bv[mf][r] = d; bi[mf][r] = n;
          } else if (d < sv[mf][r] || (d == sv[mf][r] && n < si[mf][r])) {
            sv[mf][r] = d; si[mf][r] = n;
          }
        }
    }
  }
  // reduce across the 16 column-lanes of each fragment row group
#pragma unroll
  for (int mf = 0; mf < 4; ++mf)
#pragma unroll
    for (int r = 0; r < 4; ++r) {
      float b = bv[mf][r], s = sv[mf][r];
      int i = bi[mf][r], s2i = si[mf][r];
#pragma unroll
      for (int m = 1; m < 16; m <<= 1) {
        float ob = __shfl_xor(b, m, 64);
        float os = __shfl_xor(s, m, 64);
        int oi = __shfl_xor(i, m, 64);
        int osi = __shfl_xor(s2i, m, 64);
        top2_merge(b, i, s, s2i, ob, oi, os, osi);
      }
      bv[mf][r] = b; sv[mf][r] = s; bi[mf][r] = i; si[mf][r] = s2i;
    }
  if (l15 == 0) {
#pragma unroll
    for (int mf = 0; mf < 4; ++mf)
#pragma unroll
      for (int r = 0; r < 4; ++r) {
        int row = wr * 64 + mf * 16 + lg * 4 + r;
        lb[wc][row] = bv[mf][r]; ls[wc][row] = sv[mf][r];
        li[wc][row] = bi[mf][r]; lsi[wc][row] = si[mf][r];
      }
  }
  __syncthreads();
  if (tid < 128) {
    float b = lb[0][tid], s = ls[0][tid];
    int i = li[0][tid], s2i = lsi[0][tid];
    top2_merge(b, i, s, s2i, lb[1][tid], li[1][tid], ls[1][tid], lsi[1][tid]);
    pmin[sp * MTOT + m0 + tid] = b;
    psec[sp * MTOT + m0 + tid] = s;
    pidx[sp * MTOT + m0 + tid] = i;
    psidx[sp * MTOT + m0 + tid] = s2i;
  }
}

// ---------------- fp32 fallback dist kernel ----------------
__global__ __launch_bounds__(256, 2) void vq_dist_kernel(
    const float* __restrict__ x, const float* __restrict__ emb,
    const float* __restrict__ enorm,
    float* __restrict__ pmin, float* __restrict__ psec,
    int* __restrict__ pidx, int* __restrict__ psidx) {
  __shared__ float xs[BMAIN][CC + 4];
  __shared__ float es[CC][BN];
  __shared__ float rs2[BMAIN * 16];
  __shared__ int ri2[BMAIN * 16];
  const int tid = threadIdx.x;
  const int tx = tid & 15;
  const int ty = tid >> 4;
  const int rb = blockIdx.x >> 3;
  const int sp = blockIdx.x & 7;
  const int m0 = rb * BMAIN;
  const int k0 = sp * KRANGE;

  float bv[8], sv[8];
  int bi[8], si[8];
#pragma unroll
  for (int i = 0; i < 8; ++i) {
    bv[i] = FLT_MAX; sv[i] = FLT_MAX; bi[i] = IDX_INF; si[i] = IDX_INF;
  }

  for (int kt = 0; kt < NTILE; ++kt) {
    const int kb = k0 + kt * BN;
    float acc[8][8];
#pragma unroll
    for (int i = 0; i < 8; ++i)
#pragma unroll
      for (int j = 0; j < 8; ++j) acc[i][j] = 0.f;

    for (int cc = 0; cc < CDIM; cc += CC) {
      __syncthreads();
#pragma unroll
      for (int l = 0; l < 4; ++l) {
        int f = tid + l * 256;
        int r = f >> 3, c4 = f & 7;
        float4 v = *(const float4*)(x + (size_t)(m0 + r) * CDIM + cc + c4 * 4);
        *(float4*)&xs[r][c4 * 4] = v;
      }
#pragma unroll
      for (int l = 0; l < 4; ++l) {
        int f = tid + l * 256;
        int r = f >> 5, k4 = f & 31;
        float4 v = *(const float4*)(emb + (size_t)(cc + r) * VOCAB + kb + k4 * 4);
        *(float4*)&es[r][k4 * 4] = v;
      }
      __syncthreads();
#pragma unroll
      for (int c4 = 0; c4 < CC / 4; ++c4) {
        float xa[8][4];
#pragma unroll
        for (int i = 0; i < 8; ++i)
          *(float4*)xa[i] = *(const float4*)&xs[ty * 8 + i][c4 * 4];
        float eb[4][8];
#pragma unroll
        for (int u = 0; u < 4; ++u) {
          *(float4*)&eb[u][0] = *(const float4*)&es[c4 * 4 + u][tx * 8];
          *(float4*)&eb[u][4] = *(const float4*)&es[c4 * 4 + u][tx * 8 + 4];
        }
#pragma unroll
        for (int u = 0; u < 4; ++u)
#pragma unroll
          for (int i = 0; i < 8; ++i)
#pragma unroll
            for (int j = 0; j < 8; ++j)
              acc[i][j] = fmaf(xa[i][u], eb[u][j], acc[i][j]);
      }
    }
    float en[8];
    *(float4*)&en[0] = *(const float4*)(enorm + kb + tx * 8);
    *(float4*)&en[4] = *(const float4*)(enorm + kb + tx * 8 + 4);
#pragma unroll
    for (int i = 0; i < 8; ++i)
#pragma unroll
      for (int j = 0; j < 8; ++j) {
        float d = fmaf(-2.f, acc[i][j], en[j]);
        int n = kb + tx * 8 + j;
        if (d < bv[i]) { sv[i] = bv[i]; si[i] = bi[i]; bv[i] = d; bi[i] = n; }
        else if (d < sv[i] || (d == sv[i] && n < si[i])) { sv[i] = d; si[i] = n; }
      }
  }
  __syncthreads();
  float* red_b = &xs[0][0];
  int* red_i = (int*)&es[0][0];
#pragma unroll
  for (int i = 0; i < 8; ++i) {
    int row = ty * 8 + i;
    red_b[row * 16 + tx] = bv[i];
    rs2[row * 16 + tx] = sv[i];
    red_i[row * 16 + tx] = bi[i];
    ri2[row * 16 + tx] = si[i];
  }
  __syncthreads();
  if (tid < BMAIN) {
    int row = tid;
    float B = red_b[row * 16], S = rs2[row * 16];
    int I = red_i[row * 16], SI = ri2[row * 16];
    for (int t = 1; t < 16; ++t)
      top2_merge(B, I, S, SI, red_b[row * 16 + t], red_i[row * 16 + t],
                 rs2[row * 16 + t], ri2[row * 16 + t]);
    pmin[sp * MTOT + m0 + row] = B;
    psec[sp * MTOT + m0 + row] = S;
    pidx[sp * MTOT + m0 + row] = I;
    psidx[sp * MTOT + m0 + row] = SI;
  }
}

// ---------------- fallback transpose ----------------
__global__ void vq_transpose_kernel(const float* __restrict__ emb,
                                    float* __restrict__ embT) {
  __shared__ float t[32][33];
  int bc = blockIdx.x & 7;
  int bk = blockIdx.x >> 3;
  int lx = threadIdx.x & 31, lyq = threadIdx.x >> 5;
#pragma unroll
  for (int yy = 0; yy < 4; ++yy) {
    int y = lyq * 4 + yy;
    t[y][lx] = emb[(size_t)(bc * 32 + y) * VOCAB + bk * 32 + lx];
  }
  __syncthreads();
#pragma unroll
  for (int yy = 0; yy < 4; ++yy) {
    int y = lyq * 4 + yy;
    embT[(size_t)(bk * 32 + y) * CDIM + bc * 32 + lx] = t[lx][y];
  }
}

// ---------------- merge + exact fp64 top-2 compare for near-ties + gather ----------------
__global__ void vq_gather_kernel(
    const float* __restrict__ x, const float* __restrict__ emb,
    const float* __restrict__ embT,
    const double* __restrict__ enormd,
    const float* __restrict__ pmin, const float* __restrict__ psec,
    const int* __restrict__ pidx, const int* __restrict__ psidx,
    float* __restrict__ out, int* __restrict__ counts, float* __restrict__ ssep) {
  __shared__ float xrow[CDIM];
  __shared__ double dred[2][4];
  __shared__ float warp_s[4];
  const int m = blockIdx.x;
  const int tid = threadIdx.x;

  float B = FLT_MAX, S = FLT_MAX;
  int I = IDX_INF, SI = IDX_INF;
#pragma unroll
  for (int sp2 = 0; sp2 < KSPLIT; ++sp2)
    top2_merge(B, I, S, SI, pmin[sp2 * MTOT + m], pidx[sp2 * MTOT + m],
               psec[sp2 * MTOT + m], psidx[sp2 * MTOT + m]);
  xrow[tid] = x[(size_t)m * CDIM + tid];
  __syncthreads();
  int best = I;
  if (S - B < TAU) {
    // exact fp64 compare of the two candidate codes (block-uniform)
    float xv = xrow[tid];
    double p1, p2;
    if (embT) {
      p1 = (double)xv * (double)embT[(size_t)I * CDIM + tid];
      p2 = (double)xv * (double)embT[(size_t)SI * CDIM + tid];
    } else {
      p1 = (double)xv * (double)emb[(size_t)tid * VOCAB + I];
      p2 = (double)xv * (double)emb[(size_t)tid * VOCAB + SI];
    }
#pragma unroll
    for (int off = 32; off > 0; off >>= 1) {
      p1 += __shfl_down(p1, off, 64);
      p2 += __shfl_down(p2, off, 64);
    }
    int lane = tid & 63, wid = tid >> 6;
    if (lane == 0) { dred[0][wid] = p1; dred[1][wid] = p2; }
    __syncthreads();
    double dot1 = dred[0][0] + dred[0][1] + dred[0][2] + dred[0][3];
    double dot2 = dred[1][0] + dred[1][1] + dred[1][2] + dred[1][3];
    double d1 = enormd[I] - 2.0 * dot1;
    double d2 = enormd[SI] - 2.0 * dot2;
    best = (d2 < d1 || (d2 == d1 && SI < I)) ? SI : I;
    __syncthreads();
  }
  float q = embT ? embT[(size_t)best * CDIM + tid]
                 : emb[(size_t)tid * VOCAB + best];
  float xv = xrow[tid];
  float df = q - xv;
  out[(size_t)m * CDIM + tid] = q;
  float v = df * df;
#pragma unroll
  for (int off = 32; off > 0; off >>= 1) v += __shfl_down(v, off, 64);
  int lane = tid & 63, wid = tid >> 6;
  if (lane == 0) warp_s[wid] = v;
  __syncthreads();
  if (tid == 0) {
    ssep[m] = warp_s[0] + warp_s[1] + warp_s[2] + warp_s[3];
    atomicAdd(&counts[best], 1);
  }
}

// ---------------- loss + perplexity ----------------
__global__ void vq_finalize_kernel(const float* __restrict__ ssep,
                                   const int* __restrict__ counts,
                                   float* __restrict__ out) {
  __shared__ double red[256];
  const int tid = threadIdx.x;
  double s = 0.0;
  for (int i = tid; i < MTOT; i += 256) s += (double)ssep[i];
  red[tid] = s;
  __syncthreads();
  for (int off = 128; off > 0; off >>= 1) {
    if (tid < off) red[tid] += red[tid + off];
    __syncthreads();
  }
  double sse = red[0];
  __syncthreads();
  double ps = 0.0;
  for (int k = tid; k < VOCAB; k += 256) {
    double p = (double)counts[k] / (double)MTOT;
    ps += p * log(p + 1e-10);
  }
  red[tid] = ps;
  __syncthreads();
  for (int off = 128; off > 0; off >>= 1) {
    if (tid < off) red[tid] += red[tid + off];
    __syncthreads();
  }
  if (tid == 0) {
    out[(size_t)MTOT * CDIM] = (float)(1.25 * sse / (double)((size_t)MTOT * CDIM));
    out[(size_t)MTOT * CDIM + 1] = (float)exp(-red[0]);
  }
}

extern "C" void kernel_launch(void* const* d_in, const int* in_sizes, int n_in,
                              void* d_out, int out_size, void* d_ws, size_t ws_size,
                              hipStream_t stream) {
  const float* x = (const float*)d_in[0];
  const float* emb = (const float*)d_in[1];
  float* out = (float*)d_out;
  char* ws = (char*)d_ws;

  // workspace layout (bytes)
  double* enormd = (double*)(ws);                 //        0: 65536
  float* enorm   = (float*)(ws + 65536);          //    65536: 32768
  float* pmin    = (float*)(ws + 98304);          //    98304: 524288
  float* psec    = (float*)(ws + 622592);         //   622592: 524288
  int* pidx      = (int*)(ws + 1146880);          //  1146880: 524288
  int* psidx     = (int*)(ws + 1671168);          //  1671168: 524288
  int* counts    = (int*)(ws + 2195456);          //  2195456: 32768
  float* ssep    = (float*)(ws + 2228224);        //  2228224: 65536
  const size_t base_need = 2293760;
  float* embT   = (float*)(ws + base_need);       //  2293760: 8388608
  ushort* xhi   = (ushort*)(ws + 10682368);       // 10682368: 8388608
  ushort* xlo   = (ushort*)(ws + 19070976);       // 19070976: 8388608
  ushort* ehi   = (ushort*)(ws + 27459584);       // 27459584: 4194304
  ushort* elo   = (ushort*)(ws + 31653888);       // 31653888: 4194304
  const size_t full_need = 35848192;
  const size_t embT_need = base_need + 8388608;

  hipMemsetAsync(counts, 0, VOCAB * sizeof(int), stream);
  vq_enorm_kernel<<<VOCAB / 64, 256, 0, stream>>>(emb, enorm, enormd);

  if (ws_size >= full_need) {
    vq_prep_x_kernel<<<(MTOT * CDIM) / 2048, 256, 0, stream>>>(x, xhi, xlo);
    vq_prep_embT_kernel<<<(VOCAB / 32) * (CDIM / 32), 256, 0, stream>>>(emb, embT, ehi, elo);
    vq_dist_mfma_kernel<<<(MTOT / 128) * KSPLIT, 256, 0, stream>>>(xhi, xlo, ehi, elo, enorm,
                                                                   pmin, psec, pidx, psidx);
    vq_gather_kernel<<<MTOT, 256, 0, stream>>>(x, emb, embT, enormd,
                                               pmin, psec, pidx, psidx, out, counts, ssep);
  } else {
    float* embT_fb = (ws_size >= embT_need) ? embT : nullptr;
    if (embT_fb)
      vq_transpose_kernel<<<(VOCAB / 32) * (CDIM / 32), 256, 0, stream>>>(emb, embT_fb);
    vq_dist_kernel<<<(MTOT / BMAIN) * KSPLIT, 256, 0, stream>>>(x, emb, enorm,
                                                                pmin, psec, pidx, psidx);
    vq_gather_kernel<<<MTOT, 256, 0, stream>>>(x, emb, embT_fb, enormd,
                                               pmin, psec, pidx, psidx, out, counts, ssep);
  }
  vq_finalize_kernel<<<1, 256, 0, stream>>>(ssep, counts, out);
}

// Round 4
// 434.765 us; speedup vs baseline: 3.3971x; 1.0885x over previous
//
#include <hip/hip_runtime.h>
#include <cfloat>
#include <cmath>

#define VOCAB 8192
#define MTOT 16384
#define CDIM 256
#define BM 64
#define BN 128
#define KSPLIT 8
#define KRANGE (VOCAB / KSPLIT)   // 1024
#define NKT (KRANGE / BN)         // 8 k-tiles per block
#define NCHUNK (NKT * 4)          // 32 chunks (k-tile x 4 c-chunks of 64)
#define TAU 0.05f
#define IDX_INF 0x7fffffff

typedef __attribute__((ext_vector_type(8))) short bf16x8;
typedef __attribute__((ext_vector_type(4))) float f32x4;

#define AS1 __attribute__((address_space(1)))
#define AS3 __attribute__((address_space(3)))

__device__ __forceinline__ void gl_lds16(const void* g, void* l) {
  __builtin_amdgcn_global_load_lds((const AS1 unsigned int*)g,
                                   (AS3 unsigned int*)l, 16, 0, 0);
}

__device__ inline ushort f2bf(float f) {
  unsigned u = __float_as_uint(f);
  unsigned r = (u + 0x7fffu + ((u >> 16) & 1u)) >> 16;
  return (ushort)r;
}

// merge other top-2 (ob,oi,os,osi) into mine (b,i,s,si); order by (value, index)
__device__ inline void top2_merge(float& b, int& i, float& s, int& si,
                                  float ob, int oi, float os, int osi) {
  if (ob < b || (ob == b && oi < i)) {
    if (b < os || (b == os && i < osi)) { s = b; si = i; }
    else { s = os; si = osi; }
    b = ob; i = oi;
  } else {
    if (ob < s || (ob == s && oi < si)) { s = ob; si = oi; }
  }
}

// ---------------- enorm: ||e_k||^2 in fp64 (+fp32 copy) ----------------
__global__ void vq_enorm_kernel(const float* __restrict__ emb,
                                float* __restrict__ enorm,
                                double* __restrict__ enormd) {
  __shared__ double sd[4][64];
  int tid = threadIdx.x;
  int kk = tid & 63, cg = tid >> 6;
  int k = blockIdx.x * 64 + kk;
  double s = 0.0;
  for (int c = cg * 64; c < cg * 64 + 64; ++c) {
    float v = emb[(size_t)c * VOCAB + k];
    s += (double)v * (double)v;
  }
  sd[cg][kk] = s;
  __syncthreads();
  if (cg == 0) {
    double t = sd[0][kk] + sd[1][kk] + sd[2][kk] + sd[3][kk];
    enorm[k] = (float)t;
    enormd[k] = t;
  }
}

// ---------------- transpose emb [C][K] -> embT [K][C] fp32 ----------------
__global__ void vq_prep_embT_kernel(const float* __restrict__ emb,
                                    float* __restrict__ embT) {
  __shared__ float t[32][33];
  int bc = blockIdx.x & 7;    // C/32 = 8
  int bk = blockIdx.x >> 3;   // K/32 = 256
  int lx = threadIdx.x & 31, lyq = threadIdx.x >> 5;
#pragma unroll
  for (int yy = 0; yy < 4; ++yy) {
    int y = lyq * 4 + yy;
    t[y][lx] = emb[(size_t)(bc * 32 + y) * VOCAB + bk * 32 + lx];
  }
  __syncthreads();
#pragma unroll
  for (int yy = 0; yy < 4; ++yy) {
    int y = lyq * 4 + yy;
    embT[(size_t)(bk * 32 + y) * CDIM + bc * 32 + lx] = t[lx][y];
  }
}

// ---------------- pack x -> bf16 packed-swizzled strips ----------------
// unit u (16B): rb = u>>11; q = u&2047; cc = q>>9; row = (q>>3)&63; sp = q&7
// content: x[rb*64+row][cc*64 + ((sp^(row&7))<<3) .. +8]
__global__ void vq_pack_x_kernel(const float* __restrict__ x,
                                 ushort* __restrict__ xb) {
  int u = blockIdx.x * 256 + threadIdx.x;
  int rb = u >> 11;
  int q = u & 2047;
  int cc = q >> 9, row = (q >> 3) & 63, sp = q & 7;
  int c0 = cc * 64 + ((sp ^ (row & 7)) << 3);
  const float* src = x + (size_t)(rb * 64 + row) * CDIM + c0;
  float4 v0 = *(const float4*)src;
  float4 v1 = *(const float4*)(src + 4);
  float a[8] = {v0.x, v0.y, v0.z, v0.w, v1.x, v1.y, v1.z, v1.w};
  bf16x8 h;
#pragma unroll
  for (int j = 0; j < 8; ++j) h[j] = (short)f2bf(a[j]);
  *(bf16x8*)(xb + (size_t)u * 8) = h;
}

// ---------------- pack embT -> bf16 packed-swizzled code-blocks ----------------
// unit u: kbcc = u>>10; q = u&1023; code = q>>3; sp = q&7; kb2 = kbcc>>2; cc = kbcc&3
__global__ void vq_pack_e_kernel(const float* __restrict__ embT,
                                 ushort* __restrict__ eb) {
  int u = blockIdx.x * 256 + threadIdx.x;
  int kbcc = u >> 10;
  int q = u & 1023;
  int code = q >> 3, sp = q & 7;
  int kb2 = kbcc >> 2, cc = kbcc & 3;
  int c0 = cc * 64 + ((sp ^ (code & 7)) << 3);
  const float* src = embT + (size_t)(kb2 * 128 + code) * CDIM + c0;
  float4 v0 = *(const float4*)src;
  float4 v1 = *(const float4*)(src + 4);
  float a[8] = {v0.x, v0.y, v0.z, v0.w, v1.x, v1.y, v1.z, v1.w};
  bf16x8 h;
#pragma unroll
  for (int j = 0; j < 8; ++j) h[j] = (short)f2bf(a[j]);
  *(bf16x8*)(eb + (size_t)u * 8) = h;
}

// ---------------- bf16 MFMA distance, A-resident, B-prefetch pipeline ----------------
__global__ __launch_bounds__(256, 2) void vq_dist_bf16_kernel(
    const ushort* __restrict__ xb, const ushort* __restrict__ eb,
    const float* __restrict__ enorm,
    float* __restrict__ pmin, float* __restrict__ psec,
    int* __restrict__ pidx, int* __restrict__ psidx) {
  __shared__ ushort Asw[4 * 64 * 64];       // 32 KB: [cc][row][64 cols swz]
  __shared__ ushort Bsw[2 * 128 * 64];      // 32 KB: dbuf [code][64 cols swz]
  __shared__ float lb[2][64], ls[2][64];
  __shared__ int li[2][64], lsi[2][64];

  const int tid = threadIdx.x;
  const int lane = tid & 63, wid = tid >> 6;
  const int wr = wid >> 1, wc = wid & 1;          // 2x2 wave grid
  const int l15 = lane & 15, lg = lane >> 4;
  const int rb = blockIdx.x >> 3, sp = blockIdx.x & 7;
  const int m0 = rb * BM;

  // prologue: stage full A strip (32 segs of 1KB) + B chunk 0 (16 segs)
  {
    const ushort* xs = xb + (size_t)rb * 16384;
#pragma unroll
    for (int i = 0; i < 8; ++i) {
      int seg = wid * 8 + i;
      gl_lds16(xs + (size_t)seg * 512 + lane * 8, &Asw[seg * 512]);
    }
    const ushort* bs = eb + (size_t)(sp * 8 + 0) * 4 * 8192;  // kb2 = sp*8, cc=0
#pragma unroll
    for (int i = 0; i < 4; ++i) {
      int seg = wid * 4 + i;
      gl_lds16(bs + (size_t)seg * 512 + lane * 8, &Bsw[seg * 512]);
    }
  }

  float bv[8], sv[8];
  int bi[8], si[8];
#pragma unroll
  for (int s = 0; s < 8; ++s) {
    bv[s] = FLT_MAX; sv[s] = FLT_MAX; bi[s] = IDX_INF; si[s] = IDX_INF;
  }

  f32x4 acc[2][4];

  for (int t = 0; t < NCHUNK; ++t) {
    __syncthreads();   // drains vmcnt(0): chunk-t loads visible to all waves
    // issue next chunk's B loads (overlap with compute below)
    if (t + 1 < NCHUNK) {
      int kt1 = (t + 1) >> 2, cc1 = (t + 1) & 3;
      const ushort* bs = eb + (size_t)((sp * 8 + kt1) * 4 + cc1) * 8192;
      ushort* dst = &Bsw[((t + 1) & 1) * 8192];
#pragma unroll
      for (int i = 0; i < 4; ++i) {
        int seg = wid * 4 + i;
        gl_lds16(bs + (size_t)seg * 512 + lane * 8, dst + seg * 512);
      }
    }
    const int kt = t >> 2, cc = t & 3;
    if (cc == 0) {
#pragma unroll
      for (int mf = 0; mf < 2; ++mf)
#pragma unroll
        for (int nf = 0; nf < 4; ++nf) acc[mf][nf] = (f32x4)0.f;
    }
    const ushort* Ab = &Asw[cc * 4096];
    const ushort* Bb = &Bsw[(t & 1) * 8192];
#pragma unroll
    for (int kh = 0; kh < 2; ++kh) {
      const int sl = kh * 4 + lg;
      bf16x8 af[2], bfr[4];
#pragma unroll
      for (int mf = 0; mf < 2; ++mf) {
        int row = wr * 32 + mf * 16 + l15;
        af[mf] = *(const bf16x8*)&Ab[row * 64 + ((sl ^ (row & 7)) << 3)];
      }
#pragma unroll
      for (int nf = 0; nf < 4; ++nf) {
        int code = wc * 64 + nf * 16 + l15;
        bfr[nf] = *(const bf16x8*)&Bb[code * 64 + ((sl ^ (code & 7)) << 3)];
      }
#pragma unroll
      for (int mf = 0; mf < 2; ++mf)
#pragma unroll
        for (int nf = 0; nf < 4; ++nf)
          acc[mf][nf] = __builtin_amdgcn_mfma_f32_16x16x32_bf16(af[mf], bfr[nf], acc[mf][nf], 0, 0, 0);
    }
    if (cc == 3) {
      // distances for this k-tile; update per-lane global top-2
      const int n0 = sp * KRANGE + kt * BN;
#pragma unroll
      for (int nf = 0; nf < 4; ++nf) {
        int n = n0 + wc * 64 + nf * 16 + l15;
        float en = enorm[n];
#pragma unroll
        for (int mf = 0; mf < 2; ++mf)
#pragma unroll
          for (int r = 0; r < 4; ++r) {
            float d = fmaf(-2.f, acc[mf][nf][r], en);
            int s = mf * 4 + r;
            if (d < bv[s]) {
              sv[s] = bv[s]; si[s] = bi[s]; bv[s] = d; bi[s] = n;
            } else if (d < sv[s] || (d == sv[s] && n < si[s])) {
              sv[s] = d; si[s] = n;
            }
          }
      }
    }
  }

  // cross-lane reduce over the 16 column-lanes
#pragma unroll
  for (int s = 0; s < 8; ++s) {
    float b = bv[s], sec = sv[s];
    int i = bi[s], s2i = si[s];
#pragma unroll
    for (int m = 1; m < 16; m <<= 1) {
      float ob = __shfl_xor(b, m, 64);
      float os = __shfl_xor(sec, m, 64);
      int oi = __shfl_xor(i, m, 64);
      int osi = __shfl_xor(s2i, m, 64);
      top2_merge(b, i, sec, s2i, ob, oi, os, osi);
    }
    bv[s] = b; sv[s] = sec; bi[s] = i; si[s] = s2i;
  }
  __syncthreads();
  if (l15 == 0) {
#pragma unroll
    for (int mf = 0; mf < 2; ++mf)
#pragma unroll
      for (int r = 0; r < 4; ++r) {
        int row = wr * 32 + mf * 16 + lg * 4 + r;
        int s = mf * 4 + r;
        lb[wc][row] = bv[s]; ls[wc][row] = sv[s];
        li[wc][row] = bi[s]; lsi[wc][row] = si[s];
      }
  }
  __syncthreads();
  if (tid < BM) {
    float b = lb[0][tid], s = ls[0][tid];
    int i = li[0][tid], s2i = lsi[0][tid];
    top2_merge(b, i, s, s2i, lb[1][tid], li[1][tid], ls[1][tid], lsi[1][tid]);
    pmin[sp * MTOT + m0 + tid] = b;
    psec[sp * MTOT + m0 + tid] = s;
    pidx[sp * MTOT + m0 + tid] = i;
    psidx[sp * MTOT + m0 + tid] = s2i;
  }
}

// ---------------- merge + exact fp64 16-candidate rescue + gather ----------------
__global__ void vq_gather_kernel(
    const float* __restrict__ x, const float* __restrict__ embT,
    const double* __restrict__ enormd,
    const float* __restrict__ pmin, const float* __restrict__ psec,
    const int* __restrict__ pidx, const int* __restrict__ psidx,
    float* __restrict__ out, int* __restrict__ counts, float* __restrict__ ssep) {
  __shared__ float xrow[CDIM];
  __shared__ double cd[16];
  __shared__ float warp_s[4];
  __shared__ int best_sh;
  const int m = blockIdx.x;
  const int tid = threadIdx.x;
  const int lane = tid & 63, wid = tid >> 6;

  float B = FLT_MAX, S = FLT_MAX;
  int I = IDX_INF, SI = IDX_INF;
  int cand[16];
#pragma unroll
  for (int sp2 = 0; sp2 < KSPLIT; ++sp2) {
    int i2 = pidx[sp2 * MTOT + m];
    int i3 = psidx[sp2 * MTOT + m];
    cand[2 * sp2] = i2; cand[2 * sp2 + 1] = i3;
    top2_merge(B, I, S, SI, pmin[sp2 * MTOT + m], i2, psec[sp2 * MTOT + m], i3);
  }
  xrow[tid] = x[(size_t)m * CDIM + tid];
  __syncthreads();
  int best = I;
  if (S - B < TAU) {
    // exact fp64 distance of all 16 split-candidates; 4 per wave
    for (int j = wid; j < 16; j += 4) {
      int cj = cand[j];
      double p = 0.0;
#pragma unroll
      for (int qq = 0; qq < 4; ++qq) {
        int c = lane + qq * 64;
        p += (double)xrow[c] * (double)embT[(size_t)cj * CDIM + c];
      }
#pragma unroll
      for (int off = 32; off > 0; off >>= 1) p += __shfl_down(p, off, 64);
      if (lane == 0) cd[j] = enormd[cj] - 2.0 * p;
    }
    __syncthreads();
    if (tid == 0) {
      double bd = DBL_MAX; int bidx = IDX_INF;
      for (int j = 0; j < 16; ++j) {
        int cj = cand[j];
        double dj = cd[j];
        if (dj < bd || (dj == bd && cj < bidx)) { bd = dj; bidx = cj; }
      }
      best_sh = bidx;
    }
    __syncthreads();
    best = best_sh;
  }
  float q = embT[(size_t)best * CDIM + tid];
  float xv = xrow[tid];
  float df = q - xv;
  out[(size_t)m * CDIM + tid] = q;
  float v = df * df;
#pragma unroll
  for (int off = 32; off > 0; off >>= 1) v += __shfl_down(v, off, 64);
  if (lane == 0) warp_s[wid] = v;
  __syncthreads();
  if (tid == 0) {
    ssep[m] = warp_s[0] + warp_s[1] + warp_s[2] + warp_s[3];
    atomicAdd(&counts[best], 1);
  }
}

// ---------------- loss + perplexity ----------------
__global__ void vq_finalize_kernel(const float* __restrict__ ssep,
                                   const int* __restrict__ counts,
                                   float* __restrict__ out) {
  __shared__ double red[256];
  const int tid = threadIdx.x;
  double s = 0.0;
  for (int i = tid; i < MTOT; i += 256) s += (double)ssep[i];
  red[tid] = s;
  __syncthreads();
  for (int off = 128; off > 0; off >>= 1) {
    if (tid < off) red[tid] += red[tid + off];
    __syncthreads();
  }
  double sse = red[0];
  __syncthreads();
  double ps = 0.0;
  for (int k = tid; k < VOCAB; k += 256) {
    double p = (double)counts[k] / (double)MTOT;
    ps += p * log(p + 1e-10);
  }
  red[tid] = ps;
  __syncthreads();
  for (int off = 128; off > 0; off >>= 1) {
    if (tid < off) red[tid] += red[tid + off];
    __syncthreads();
  }
  if (tid == 0) {
    out[(size_t)MTOT * CDIM] = (float)(1.25 * sse / (double)((size_t)MTOT * CDIM));
    out[(size_t)MTOT * CDIM + 1] = (float)exp(-red[0]);
  }
}

extern "C" void kernel_launch(void* const* d_in, const int* in_sizes, int n_in,
                              void* d_out, int out_size, void* d_ws, size_t ws_size,
                              hipStream_t stream) {
  const float* x = (const float*)d_in[0];
  const float* emb = (const float*)d_in[1];
  float* out = (float*)d_out;
  char* ws = (char*)d_ws;

  // workspace layout (bytes)
  double* enormd = (double*)(ws);                 //        0: 65536
  float* enorm   = (float*)(ws + 65536);          //    65536: 32768
  float* pmin    = (float*)(ws + 98304);          //    98304: 524288
  float* psec    = (float*)(ws + 622592);         //   622592: 524288
  int* pidx      = (int*)(ws + 1146880);          //  1146880: 524288
  int* psidx     = (int*)(ws + 1671168);          //  1671168: 524288
  int* counts    = (int*)(ws + 2195456);          //  2195456: 32768
  float* ssep    = (float*)(ws + 2228224);        //  2228224: 65536
  float* embT    = (float*)(ws + 2293760);        //  2293760: 8388608
  ushort* xb     = (ushort*)(ws + 10682368);      // 10682368: 8388608
  ushort* eb     = (ushort*)(ws + 19070976);      // 19070976: 4194304
  // total need: 23265280 bytes (harness provides >= 35 MB, proven round 1-3)

  hipMemsetAsync(counts, 0, VOCAB * sizeof(int), stream);
  vq_enorm_kernel<<<VOCAB / 64, 256, 0, stream>>>(emb, enorm, enormd);
  vq_prep_embT_kernel<<<(VOCAB / 32) * (CDIM / 32), 256, 0, stream>>>(emb, embT);
  vq_pack_e_kernel<<<(VOCAB * CDIM / 8) / 256, 256, 0, stream>>>(embT, eb);
  vq_pack_x_kernel<<<(MTOT * CDIM / 8) / 256, 256, 0, stream>>>(x, xb);
  vq_dist_bf16_kernel<<<(MTOT / BM) * KSPLIT, 256, 0, stream>>>(xb, eb, enorm,
                                                                pmin, psec, pidx, psidx);
  vq_gather_kernel<<<MTOT, 256, 0, stream>>>(x, embT, enormd,
                                             pmin, psec, pidx, psidx, out, counts, ssep);
  vq_finalize_kernel<<<1, 256, 0, stream>>>(ssep, counts, out);
}

// Round 5
// 169.285 us; speedup vs baseline: 8.7245x; 2.5682x over previous
//
#include <hip/hip_runtime.h>
#include <cfloat>
#include <cmath>

#define VOCAB 8192
#define MTOT 16384
#define CDIM 256
#define BM 64
#define KSPLIT 8
#define KRANGE (VOCAB / KSPLIT)   // 1024
#define TAU 0.1f
#define IDX_INF 0x7fffffff

typedef __attribute__((ext_vector_type(8))) short bf16x8;
typedef __attribute__((ext_vector_type(4))) float f32x4;

#define AS1 __attribute__((address_space(1)))
#define AS3 __attribute__((address_space(3)))

__device__ __forceinline__ void gl_lds16(const void* g, void* l) {
  __builtin_amdgcn_global_load_lds((const AS1 unsigned int*)g,
                                   (AS3 unsigned int*)l, 16, 0, 0);
}

__device__ inline ushort f2bf(float f) {
  unsigned u = __float_as_uint(f);
  unsigned r = (u + 0x7fffu + ((u >> 16) & 1u)) >> 16;
  return (ushort)r;
}

// insert key a into sorted quadruple k0<=k1<=k2<=k3
__device__ __forceinline__ void ins4(uint& k0, uint& k1, uint& k2, uint& k3, uint a) {
  uint t;
  t = min(k0, a); a = max(k0, a); k0 = t;
  t = min(k1, a); a = max(k1, a); k1 = t;
  t = min(k2, a); a = max(k2, a); k2 = t;
  k3 = min(k3, a);
}

// ---------------- enorm: ||e_k||^2 + 16 in fp32, exact fp64 copy ----------------
__global__ void vq_enorm_kernel(const float* __restrict__ emb,
                                float* __restrict__ enorm16,
                                double* __restrict__ enormd) {
  __shared__ double sd[4][64];
  int tid = threadIdx.x;
  int kk = tid & 63, cg = tid >> 6;
  int k = blockIdx.x * 64 + kk;
  double s = 0.0;
  for (int c = cg * 64; c < cg * 64 + 64; ++c) {
    float v = emb[(size_t)c * VOCAB + k];
    s += (double)v * (double)v;
  }
  sd[cg][kk] = s;
  __syncthreads();
  if (cg == 0) {
    double t = sd[0][kk] + sd[1][kk] + sd[2][kk] + sd[3][kk];
    enorm16[k] = (float)t + 16.0f;   // offset keeps MFMA-accumulated distance positive
    enormd[k] = t;
  }
}

// ---------------- transpose emb [C][K] -> embT [K][C] fp32 ----------------
__global__ void vq_prep_embT_kernel(const float* __restrict__ emb,
                                    float* __restrict__ embT) {
  __shared__ float t[32][33];
  int bc = blockIdx.x & 7;    // C/32 = 8
  int bk = blockIdx.x >> 3;   // K/32 = 256
  int lx = threadIdx.x & 31, lyq = threadIdx.x >> 5;
#pragma unroll
  for (int yy = 0; yy < 4; ++yy) {
    int y = lyq * 4 + yy;
    t[y][lx] = emb[(size_t)(bc * 32 + y) * VOCAB + bk * 32 + lx];
  }
  __syncthreads();
#pragma unroll
  for (int yy = 0; yy < 4; ++yy) {
    int y = lyq * 4 + yy;
    embT[(size_t)(bk * 32 + y) * CDIM + bc * 32 + lx] = t[lx][y];
  }
}

// ---------------- pack -2x -> bf16 packed-swizzled strips ----------------
// unit u (16B): rb=u>>11; q=u&2047; cc=q>>9; row=(q>>3)&63; sw=q&7
// content: -2*x[rb*64+row][cc*64 + ((sw^(row&7))<<3) .. +8]
__global__ void vq_pack_x_kernel(const float* __restrict__ x,
                                 ushort* __restrict__ xb) {
  int u = blockIdx.x * 256 + threadIdx.x;
  int rb = u >> 11;
  int q = u & 2047;
  int cc = q >> 9, row = (q >> 3) & 63, sw = q & 7;
  int c0 = cc * 64 + ((sw ^ (row & 7)) << 3);
  const float* src = x + (size_t)(rb * 64 + row) * CDIM + c0;
  float4 v0 = *(const float4*)src;
  float4 v1 = *(const float4*)(src + 4);
  float a[8] = {v0.x, v0.y, v0.z, v0.w, v1.x, v1.y, v1.z, v1.w};
  bf16x8 h;
#pragma unroll
  for (int j = 0; j < 8; ++j) h[j] = (short)f2bf(-2.0f * a[j]);
  *(bf16x8*)(xb + (size_t)u * 8) = h;
}

// ---------------- pack embT -> bf16 packed-swizzled code-blocks ----------------
__global__ void vq_pack_e_kernel(const float* __restrict__ embT,
                                 ushort* __restrict__ eb) {
  int u = blockIdx.x * 256 + threadIdx.x;
  int kbcc = u >> 10;
  int q = u & 1023;
  int code = q >> 3, sw = q & 7;
  int kb2 = kbcc >> 2, cc = kbcc & 3;
  int c0 = cc * 64 + ((sw ^ (code & 7)) << 3);
  const float* src = embT + (size_t)(kb2 * 128 + code) * CDIM + c0;
  float4 v0 = *(const float4*)src;
  float4 v1 = *(const float4*)(src + 4);
  float a[8] = {v0.x, v0.y, v0.z, v0.w, v1.x, v1.y, v1.z, v1.w};
  bf16x8 h;
#pragma unroll
  for (int j = 0; j < 8; ++j) h[j] = (short)f2bf(a[j]);
  *(bf16x8*)(eb + (size_t)u * 8) = h;
}

// ---------------- bf16 MFMA distance, packed-key stream minima -> top-4/split ----------------
__global__ __launch_bounds__(256, 2) void vq_dist_bf16_kernel(
    const ushort* __restrict__ xb, const ushort* __restrict__ eb,
    const float* __restrict__ en16g, uint4* __restrict__ pk) {
  __shared__ ushort Asw[4 * 64 * 64];       // 32 KB: [cc][row][64 cols swz]
  __shared__ ushort Bsw[2 * 128 * 64];      // 32 KB: parity dbuf [code][64 cols swz]

  const int tid = threadIdx.x;
  const int lane = tid & 63, wid = tid >> 6;
  const int wr = wid >> 1, wc = wid & 1;    // 2x2 wave grid
  const int l15 = lane & 15, lg = lane >> 4;
  const int rb = blockIdx.x >> 3, sp = blockIdx.x & 7;
  const int m0 = rb * BM;

  // hoisted LDS byte-offsets for the 12 fragment reads
  uint baA[2][2], baB[4][2];
#pragma unroll
  for (int mf = 0; mf < 2; ++mf) {
    int row = wr * 32 + mf * 16 + l15;
#pragma unroll
    for (int kh = 0; kh < 2; ++kh)
      baA[mf][kh] = row * 128 + ((((kh * 4) + lg) ^ (row & 7)) << 4);
  }
#pragma unroll
  for (int nf = 0; nf < 4; ++nf) {
    int code = wc * 64 + nf * 16 + l15;
#pragma unroll
    for (int kh = 0; kh < 2; ++kh)
      baB[nf][kh] = code * 128 + ((((kh * 4) + lg) ^ (code & 7)) << 4);
  }

  const uint plB = wid * 2048 + lane * 8;   // ushort offset of this lane's staging slot
  const ushort* ebk = eb + (size_t)sp * 262144;

  // prologue: stage full A strip (8 segs/wave) + B chunk 0 (4 segs/wave)
  {
    const ushort* xs = xb + (size_t)rb * 16384;
#pragma unroll
    for (int i = 0; i < 8; ++i) {
      int seg = wid * 8 + i;
      gl_lds16(xs + (size_t)seg * 512 + lane * 8, &Asw[seg * 512]);
    }
#pragma unroll
    for (int i = 0; i < 4; ++i)
      gl_lds16(ebk + plB + i * 512, &Bsw[(wid * 4 + i) * 512]);
  }

  const int nb = sp * KRANGE + wc * 64 + l15;
  uint kmin[8];
#pragma unroll
  for (int s = 0; s < 8; ++s) kmin[s] = 0xffffffffu;

  f32x4 acc[2][4];

  for (int kt = 0; kt < 8; ++kt) {
    // per-k-tile: accumulator init = ||e||^2 + 16 (distance materializes in acc)
    float e16[4];
#pragma unroll
    for (int nf = 0; nf < 4; ++nf) e16[nf] = en16g[nb + kt * 128 + nf * 16];
#pragma unroll
    for (int mf = 0; mf < 2; ++mf)
#pragma unroll
      for (int nf = 0; nf < 4; ++nf)
        acc[mf][nf] = (f32x4){e16[nf], e16[nf], e16[nf], e16[nf]};

#pragma unroll
    for (int cc = 0; cc < 4; ++cc) {
      __syncthreads();   // drains staging of chunk (kt,cc)
      // issue next chunk's staging (overlaps compute below)
      if (cc < 3 || kt < 7) {
        const ushort* src = ebk + (cc + 1) * 8192 + plB;
        ushort* dst = &Bsw[((cc + 1) & 1) * 8192 + (wid * 4) * 512];
#pragma unroll
        for (int i = 0; i < 4; ++i)
          gl_lds16(src + i * 512, dst + i * 512);
      }
      const char* Ab = (const char*)Asw + cc * 8192;
      const char* Bb = (const char*)Bsw + (cc & 1) * 16384;
#pragma unroll
      for (int kh = 0; kh < 2; ++kh) {
        bf16x8 af[2], bfr[4];
#pragma unroll
        for (int mf = 0; mf < 2; ++mf)
          af[mf] = *(const bf16x8*)(Ab + baA[mf][kh]);
#pragma unroll
        for (int nf = 0; nf < 4; ++nf)
          bfr[nf] = *(const bf16x8*)(Bb + baB[nf][kh]);
#pragma unroll
        for (int mf = 0; mf < 2; ++mf)
#pragma unroll
          for (int nf = 0; nf < 4; ++nf)
            acc[mf][nf] = __builtin_amdgcn_mfma_f32_16x16x32_bf16(af[mf], bfr[nf], acc[mf][nf], 0, 0, 0);
      }
    }
    // fold k-tile distances into per-stream packed-key minima (3 VALU/elem)
#pragma unroll
    for (int nf = 0; nf < 4; ++nf) {
      uint nk = (uint)(nb + kt * 128 + nf * 16);
#pragma unroll
      for (int mf = 0; mf < 2; ++mf)
#pragma unroll
        for (int r = 0; r < 4; ++r) {
          uint u = __float_as_uint(acc[mf][nf][r]) & 0xffffe000u;
          kmin[mf * 4 + r] = min(kmin[mf * 4 + r], u | nk);
        }
    }
    ebk += 32768;
  }

  // union of 32 stream-minima per row -> sorted top-4 -> pk
  __syncthreads();
  uint* karr = (uint*)Asw;                   // [2][64] rows x stride 17
#pragma unroll
  for (int mf = 0; mf < 2; ++mf)
#pragma unroll
    for (int r = 0; r < 4; ++r) {
      int row = wr * 32 + mf * 16 + lg * 4 + r;
      karr[(wc * 64 + row) * 17 + l15] = kmin[mf * 4 + r];
    }
  __syncthreads();
  if (tid < BM) {
    uint k0 = ~0u, k1 = ~0u, k2 = ~0u, k3 = ~0u;
    const uint* r0 = karr + tid * 17;
    const uint* r1 = karr + (64 + tid) * 17;
#pragma unroll
    for (int j = 0; j < 16; ++j) ins4(k0, k1, k2, k3, r0[j]);
#pragma unroll
    for (int j = 0; j < 16; ++j) ins4(k0, k1, k2, k3, r1[j]);
    pk[(size_t)sp * MTOT + m0 + tid] = make_uint4(k0, k1, k2, k3);
  }
}

// ---------------- merge 32 candidates + fp64 rescue + gather (1 wave / row) ----------------
__global__ void vq_gather_kernel(
    const float* __restrict__ x, const float* __restrict__ embT,
    const double* __restrict__ enormd, const uint4* __restrict__ pk,
    float* __restrict__ out, int* __restrict__ counts, float* __restrict__ ssep) {
  const int wid = threadIdx.x >> 6, lane = threadIdx.x & 63;
  const int m = blockIdx.x * 4 + wid;

  const float4 xq = *(const float4*)(x + (size_t)m * CDIM + lane * 4);

  float bd = FLT_MAX, sd = FLT_MAX;
  uint bkey = 0xffffffffu;
#pragma unroll
  for (int sp2 = 0; sp2 < KSPLIT; ++sp2) {
    uint4 kv = pk[(size_t)sp2 * MTOT + m];
    uint ks[4] = {kv.x, kv.y, kv.z, kv.w};
#pragma unroll
    for (int j = 0; j < 4; ++j) {
      uint k = ks[j];
      float dq = __uint_as_float(k & 0xffffe000u);
      if (k < bkey) { sd = bd; bd = dq; bkey = k; }
      else sd = fminf(sd, dq);
    }
  }
  int best = (int)(bkey & 8191u);
  if (sd - bd < TAU) {   // ambiguous: exact fp64 over all 32 candidates (wave-uniform)
    double bD = DBL_MAX;
    int bn = IDX_INF;
    for (int sp2 = 0; sp2 < KSPLIT; ++sp2) {
      uint4 kv = pk[(size_t)sp2 * MTOT + m];
      uint ks[4] = {kv.x, kv.y, kv.z, kv.w};
#pragma unroll
      for (int j = 0; j < 4; ++j) {
        int cj = (int)(ks[j] & 8191u);
        const float4 ev = *(const float4*)(embT + (size_t)cj * CDIM + lane * 4);
        double p = (double)xq.x * ev.x + (double)xq.y * ev.y
                 + (double)xq.z * ev.z + (double)xq.w * ev.w;
#pragma unroll
        for (int off = 1; off < 64; off <<= 1) p += __shfl_xor(p, off, 64);
        double dj = enormd[cj] - 2.0 * p;
        if (dj < bD || (dj == bD && cj < bn)) { bD = dj; bn = cj; }
      }
    }
    best = bn;
  }
  const float4 ev = *(const float4*)(embT + (size_t)best * CDIM + lane * 4);
  *(float4*)(out + (size_t)m * CDIM + lane * 4) = ev;
  float dx = ev.x - xq.x, dy = ev.y - xq.y, dz = ev.z - xq.z, dw = ev.w - xq.w;
  float v = dx * dx + dy * dy + dz * dz + dw * dw;
#pragma unroll
  for (int off = 32; off > 0; off >>= 1) v += __shfl_down(v, off, 64);
  if (lane == 0) {
    ssep[m] = v;
    atomicAdd(&counts[best], 1);
  }
}

// ---------------- loss + perplexity, two-stage deterministic ----------------
__global__ void vq_final1_kernel(const float* __restrict__ ssep,
                                 const int* __restrict__ counts,
                                 double* __restrict__ part) {
  __shared__ double red[256];
  const int tid = threadIdx.x, b = blockIdx.x;
  red[tid] = (double)ssep[b * 256 + tid];
  __syncthreads();
  for (int off = 128; off > 0; off >>= 1) {
    if (tid < off) red[tid] += red[tid + off];
    __syncthreads();
  }
  if (tid == 0) part[b] = red[0];
  __syncthreads();
  double e = 0.0;
  if (tid < 128) {
    double p = (double)counts[b * 128 + tid] / (double)MTOT;
    e = p * log(p + 1e-10);
  }
  red[tid] = e;
  __syncthreads();
  for (int off = 128; off > 0; off >>= 1) {
    if (tid < off) red[tid] += red[tid + off];
    __syncthreads();
  }
  if (tid == 0) part[64 + b] = red[0];
}

__global__ void vq_final2_kernel(const double* __restrict__ part,
                                 float* __restrict__ out) {
  const int lane = threadIdx.x;   // 64 threads
  double s = part[lane], e = part[64 + lane];
#pragma unroll
  for (int off = 32; off > 0; off >>= 1) {
    s += __shfl_down(s, off, 64);
    e += __shfl_down(e, off, 64);
  }
  if (lane == 0) {
    out[(size_t)MTOT * CDIM] = (float)(1.25 * s / (double)((size_t)MTOT * CDIM));
    out[(size_t)MTOT * CDIM + 1] = (float)exp(-e);
  }
}

extern "C" void kernel_launch(void* const* d_in, const int* in_sizes, int n_in,
                              void* d_out, int out_size, void* d_ws, size_t ws_size,
                              hipStream_t stream) {
  const float* x = (const float*)d_in[0];
  const float* emb = (const float*)d_in[1];
  float* out = (float*)d_out;
  char* ws = (char*)d_ws;

  // workspace layout (bytes)
  double* enormd = (double*)(ws);                 //        0: 65536
  float* enorm16 = (float*)(ws + 65536);          //    65536: 32768
  uint4* pk      = (uint4*)(ws + 98304);          //    98304: 2097152
  int* counts    = (int*)(ws + 2195456);          //  2195456: 32768
  float* ssep    = (float*)(ws + 2228224);        //  2228224: 65536
  double* part   = (double*)(ws + 2293760);       //  2293760: 1024
  float* embT    = (float*)(ws + 2294784);        //  2294784: 8388608
  ushort* xb     = (ushort*)(ws + 10683392);      // 10683392: 8388608
  ushort* eb     = (ushort*)(ws + 19072000);      // 19072000: 4194304
  // total 23266304 bytes (< 35 MB proven available in rounds 1-4)

  hipMemsetAsync(counts, 0, VOCAB * sizeof(int), stream);
  vq_enorm_kernel<<<VOCAB / 64, 256, 0, stream>>>(emb, enorm16, enormd);
  vq_prep_embT_kernel<<<(VOCAB / 32) * (CDIM / 32), 256, 0, stream>>>(emb, embT);
  vq_pack_e_kernel<<<(VOCAB * CDIM / 8) / 256, 256, 0, stream>>>(embT, eb);
  vq_pack_x_kernel<<<(MTOT * CDIM / 8) / 256, 256, 0, stream>>>(x, xb);
  vq_dist_bf16_kernel<<<(MTOT / BM) * KSPLIT, 256, 0, stream>>>(xb, eb, enorm16, pk);
  vq_gather_kernel<<<MTOT / 4, 256, 0, stream>>>(x, embT, enormd, pk, out, counts, ssep);
  vq_final1_kernel<<<64, 256, 0, stream>>>(ssep, counts, part);
  vq_final2_kernel<<<1, 64, 0, stream>>>(part, out);
}